// Round 5
// baseline (1451.496 us; speedup 1.0000x reference)
//
#include <hip/hip_runtime.h>
#include <hip/hip_bf16.h>

#define DIN 128
#define DH 32
#define DOUT 2
#define NPB 128            // nodes per bucket
#define NPB_SHIFT 7
#define NBUK_MAX 1024      // supports n <= 131072 (17-bit src packing)
#define FILL_EDGES 4096    // edges per binning block

// ---------------------------------------------------------------------------
// workspace (~20.8 MB, budget ~26.8 MB):
//   deg    int[n]; dinv float[n]; gcnt/gbase/gcur int[NBUK_MAX]
//   binned uint[E]  (dst&127)<<17 | src, grouped by 128-node bucket
//   mqc    bf16[n*32]  dinv-scaled layer-1 messages
//   m2q    float2[n]   dinv-scaled layer-2 messages
// ---------------------------------------------------------------------------

__device__ inline unsigned short f2bf(float f) {
    unsigned int u = __float_as_uint(f);
    u = (u + 0x7FFFu + ((u >> 16) & 1u)) >> 16;
    return (unsigned short)u;
}
__device__ inline float bflo(unsigned int u) { return __uint_as_float(u << 16); }
__device__ inline float bfhi(unsigned int u) { return __uint_as_float(u & 0xFFFF0000u); }
__device__ inline float bf2f(unsigned short b) {
    return __uint_as_float(((unsigned int)b) << 16);
}

__global__ void zero_kernel(int* __restrict__ deg, int* __restrict__ gcnt, int n, int nbuk) {
    int i = blockIdx.x * blockDim.x + threadIdx.x;
    if (i < n) deg[i] = 0;
    if (i < nbuk) gcnt[i] = 0;
}

__global__ void hist_kernel(const int* __restrict__ dst, int* __restrict__ deg,
                            int* __restrict__ gcnt, int e, int nbuk) {
    __shared__ int lcnt[NBUK_MAX];
    int t = threadIdx.x;
    for (int i = t; i < nbuk; i += 256) lcnt[i] = 0;
    __syncthreads();
    int e0 = blockIdx.x * FILL_EDGES;
    int m = min(FILL_EDGES, e - e0);
    for (int i = t; i < m; i += 256) {
        int d = dst[e0 + i];
        atomicAdd(&deg[d], 1);
        atomicAdd(&lcnt[d >> NPB_SHIFT], 1);
    }
    __syncthreads();
    for (int i = t; i < nbuk; i += 256)
        if (lcnt[i]) atomicAdd(&gcnt[i], lcnt[i]);
}

__global__ void dinv_kernel(const int* __restrict__ deg, float* __restrict__ dinv, int n) {
    int i = blockIdx.x * blockDim.x + threadIdx.x;
    if (i < n) dinv[i] = rsqrtf((float)(deg[i] + 1));
}

__global__ void scan_kernel(const int* __restrict__ gcnt, int* __restrict__ gbase,
                            int* __restrict__ gcur, int nbuk) {
    __shared__ int sd[256];
    int t = threadIdx.x;
    int v[4], s = 0;
#pragma unroll
    for (int k = 0; k < 4; ++k) {
        int i = 4 * t + k;
        v[k] = (i < nbuk) ? gcnt[i] : 0;
        s += v[k];
    }
    sd[t] = s;
    __syncthreads();
    for (int off = 1; off < 256; off <<= 1) {
        int x = (t >= off) ? sd[t - off] : 0;
        __syncthreads();
        sd[t] += x;
        __syncthreads();
    }
    int run = sd[t] - s;
#pragma unroll
    for (int k = 0; k < 4; ++k) {
        int i = 4 * t + k;
        if (i < nbuk) { gbase[i] = run; gcur[i] = run; }
        run += v[k];
    }
}

// LDS counting-sort of 4096 edges by bucket, bulk-append to global regions
__global__ void binfill_kernel(const int* __restrict__ src, const int* __restrict__ dst,
                               int* __restrict__ gcur, unsigned int* __restrict__ binned,
                               int e, int nbuk) {
    __shared__ int cnt[NBUK_MAX];
    __shared__ int pos[NBUK_MAX];
    __shared__ int gb[NBUK_MAX];
    __shared__ unsigned int sorted[FILL_EDGES];
    __shared__ unsigned short aux[FILL_EDGES];
    __shared__ int stmp[256];

    int t = threadIdx.x;
    int e0 = blockIdx.x * FILL_EDGES;
    int m = min(FILL_EDGES, e - e0);

    for (int i = t; i < nbuk; i += 256) cnt[i] = 0;
    __syncthreads();
    for (int i = t; i < m; i += 256) atomicAdd(&cnt[dst[e0 + i] >> NPB_SHIFT], 1);
    __syncthreads();

    int v[4], s = 0;
#pragma unroll
    for (int k = 0; k < 4; ++k) {
        int i = 4 * t + k;
        v[k] = (i < nbuk) ? cnt[i] : 0;
        s += v[k];
    }
    stmp[t] = s;
    __syncthreads();
    for (int off = 1; off < 256; off <<= 1) {
        int x = (t >= off) ? stmp[t - off] : 0;
        __syncthreads();
        stmp[t] += x;
        __syncthreads();
    }
    int run = stmp[t] - s;
#pragma unroll
    for (int k = 0; k < 4; ++k) {
        int i = 4 * t + k;
        if (i < nbuk) pos[i] = run;
        run += v[k];
    }
    __syncthreads();

    for (int i = t; i < m; i += 256) {
        int d = dst[e0 + i];
        int sv = src[e0 + i];
        int b = d >> NPB_SHIFT;
        int r = atomicAdd(&pos[b], 1);
        sorted[r] = ((unsigned int)(d & (NPB - 1)) << 17) | (unsigned int)sv;
        aux[r] = (unsigned short)b;
    }
    __syncthreads();

    for (int b = t; b < nbuk; b += 256) {
        int c = cnt[b];
        gb[b] = c ? atomicAdd(&gcur[b], c) : 0;
    }
    __syncthreads();

    for (int i = t; i < m; i += 256) {
        int b = aux[i];
        int start = pos[b] - cnt[b];
        binned[gb[b] + (i - start)] = sorted[i];
    }
}

// mqc[r][c] = (x[r]·W1[:,c]) * dinv[r], bf16.  128 rows/block,
// thread = (rq 0..31)x(cg 0..7) owning 4 rows x 4 cols outer product.
__global__ void gemm1_kernel(const float* __restrict__ x, const float* __restrict__ W1,
                             const float* __restrict__ dinv,
                             unsigned short* __restrict__ mqc, int n) {
    __shared__ float4 Wl4[DIN * 8];   // 16 KB, [k][cg]
    int t = threadIdx.x;
    for (int i = t; i < DIN * 8; i += 256) Wl4[i] = ((const float4*)W1)[i];
    __syncthreads();

    const int rq = t >> 3, cg = t & 7;
    const int r0 = blockIdx.x * 128 + rq * 4;
    const float4* x4 = (const float4*)x;

    float4 a0 = {0,0,0,0}, a1 = {0,0,0,0}, a2 = {0,0,0,0}, a3 = {0,0,0,0};
    const bool full = (r0 + 3 < n);

#pragma unroll 8
    for (int kk = 0; kk < 32; ++kk) {
        float4 z = {0,0,0,0};
        float4 x0 = z, x1 = z, x2 = z, x3 = z;
        if (full) {
            x0 = x4[(size_t)(r0 + 0) * 32 + kk];
            x1 = x4[(size_t)(r0 + 1) * 32 + kk];
            x2 = x4[(size_t)(r0 + 2) * 32 + kk];
            x3 = x4[(size_t)(r0 + 3) * 32 + kk];
        } else {
            if (r0 + 0 < n) x0 = x4[(size_t)(r0 + 0) * 32 + kk];
            if (r0 + 1 < n) x1 = x4[(size_t)(r0 + 1) * 32 + kk];
            if (r0 + 2 < n) x2 = x4[(size_t)(r0 + 2) * 32 + kk];
            if (r0 + 3 < n) x3 = x4[(size_t)(r0 + 3) * 32 + kk];
        }
        float4 w0 = Wl4[(4 * kk + 0) * 8 + cg];
        float4 w1 = Wl4[(4 * kk + 1) * 8 + cg];
        float4 w2 = Wl4[(4 * kk + 2) * 8 + cg];
        float4 w3 = Wl4[(4 * kk + 3) * 8 + cg];
#define ACC(A, X) \
        A.x += X.x * w0.x + X.y * w1.x + X.z * w2.x + X.w * w3.x; \
        A.y += X.x * w0.y + X.y * w1.y + X.z * w2.y + X.w * w3.y; \
        A.z += X.x * w0.z + X.y * w1.z + X.z * w2.z + X.w * w3.z; \
        A.w += X.x * w0.w + X.y * w1.w + X.z * w2.w + X.w * w3.w;
        ACC(a0, x0) ACC(a1, x1) ACC(a2, x2) ACC(a3, x3)
#undef ACC
    }

#define STORE(I, A) \
    if (r0 + I < n) { \
        float di = dinv[r0 + I]; \
        ushort4 sv; \
        sv.x = f2bf(A.x * di); sv.y = f2bf(A.y * di); \
        sv.z = f2bf(A.z * di); sv.w = f2bf(A.w * di); \
        *(ushort4*)&mqc[(size_t)(r0 + I) * DH + 4 * cg] = sv; \
    }
    STORE(0, a0) STORE(1, a1) STORE(2, a2) STORE(3, a3)
#undef STORE
}

// one block per bucket, EDGE-PARALLEL: each thread owns one edge, loads the
// 64B mqc row itself, 32 unrolled LDS atomics with rotation swizzle
// addr = dl*32 + ((dim + dl) & 31)  ->  bank = (dim + dl) & 31  (spread).
__global__ void agg1_kernel(const int* __restrict__ gbase, const int* __restrict__ gcnt,
                            const unsigned int* __restrict__ binned,
                            const unsigned short* __restrict__ mqc,
                            const float* __restrict__ dinv,
                            const float* __restrict__ b1, const float* __restrict__ W2,
                            float2* __restrict__ m2q, int n) {
    __shared__ float acc[NPB * DH];   // 16 KB
    int t = threadIdx.x;
    int b = blockIdx.x;
    for (int i = t; i < NPB * DH; i += 256) acc[i] = 0.f;
    __syncthreads();

    const int beg = gbase[b];
    const int cntb = gcnt[b];

    for (int i = t; i < cntb; i += 256) {
        unsigned int entry = binned[beg + i];
        int sv = (int)(entry & 0x1FFFFu);
        int dl = (int)(entry >> 17);
        const uint4* row = (const uint4*)(mqc + (size_t)sv * DH);
        uint4 q0 = row[0], q1 = row[1], q2 = row[2], q3 = row[3];
        float* ar = acc + dl * DH;
        int rot = dl & 31;
        unsigned int w[16] = {q0.x, q0.y, q0.z, q0.w, q1.x, q1.y, q1.z, q1.w,
                              q2.x, q2.y, q2.z, q2.w, q3.x, q3.y, q3.z, q3.w};
#pragma unroll
        for (int d = 0; d < 16; ++d) {
            atomicAdd(&ar[(2 * d + rot) & 31], bflo(w[d]));
            atomicAdd(&ar[(2 * d + 1 + rot) & 31], bfhi(w[d]));
        }
    }
    __syncthreads();

    // epilogue: add self message, ReLU, W2 transform, emit m2q
    const int lane = t & 31;
    const int half = t >> 5;
    const int r0 = b << NPB_SHIFT;
    for (int rl = half; rl < NPB; rl += 8) {
        int r = r0 + rl;
        if (r >= n) break;
        int rot = rl & 31;
        float di = dinv[r];
        float a = acc[rl * DH + ((lane + rot) & 31)] + bf2f(mqc[(size_t)r * DH + lane]);
        float h = fmaxf(di * a + b1[lane], 0.0f);
        float p0 = h * W2[lane * DOUT + 0];
        float p1 = h * W2[lane * DOUT + 1];
#pragma unroll
        for (int off = 16; off > 0; off >>= 1) {
            p0 += __shfl_down(p0, off, 32);
            p1 += __shfl_down(p1, off, 32);
        }
        if (lane == 0) m2q[r] = make_float2(di * p0, di * p1);
    }
}

// one block per bucket: layer-2 aggregate + bias, write out directly
__global__ void agg2_kernel(const int* __restrict__ gbase, const int* __restrict__ gcnt,
                            const unsigned int* __restrict__ binned,
                            const float2* __restrict__ m2q,
                            const float* __restrict__ dinv, const float* __restrict__ b2,
                            float* __restrict__ out, int n) {
    __shared__ float acc0[NPB], acc1[NPB];
    int t = threadIdx.x;
    int b = blockIdx.x;
    for (int i = t; i < NPB; i += 256) { acc0[i] = 0.f; acc1[i] = 0.f; }
    __syncthreads();

    const int beg = gbase[b];
    const int cntb = gcnt[b];
    for (int i = t; i < cntb; i += 256) {
        unsigned int entry = binned[beg + i];
        int sv = (int)(entry & 0x1FFFFu);
        int dl = (int)(entry >> 17);
        float2 v = m2q[sv];
        atomicAdd(&acc0[dl], v.x);
        atomicAdd(&acc1[dl], v.y);
    }
    __syncthreads();

    int r0 = b << NPB_SHIFT;
    for (int rl = t; rl < NPB; rl += 256) {
        int r = r0 + rl;
        if (r < n) {
            float di = dinv[r];
            float2 self = m2q[r];
            out[(size_t)r * DOUT + 0] = di * (acc0[rl] + self.x) + b2[0];
            out[(size_t)r * DOUT + 1] = di * (acc1[rl] + self.y) + b2[1];
        }
    }
}

extern "C" void kernel_launch(void* const* d_in, const int* in_sizes, int n_in,
                              void* d_out, int out_size, void* d_ws, size_t ws_size,
                              hipStream_t stream) {
    const float* x  = (const float*)d_in[0];
    const int*   ei = (const int*)d_in[1];
    const float* W1 = (const float*)d_in[2];
    const float* b1 = (const float*)d_in[3];
    const float* W2 = (const float*)d_in[4];
    const float* b2 = (const float*)d_in[5];
    float* out = (float*)d_out;

    const int n = in_sizes[0] / DIN;
    const int e = in_sizes[1] / 2;
    const int* src = ei;
    const int* dst = ei + e;
    const int nbuk = (n + NPB - 1) >> NPB_SHIFT;   // 782 for n=100000

    char* ws = (char*)d_ws;
    int* deg      = (int*)ws;            ws += (size_t)n * 4;
    float* dinv   = (float*)ws;          ws += (size_t)n * 4;
    int* gcnt     = (int*)ws;            ws += NBUK_MAX * 4;
    int* gbase    = (int*)ws;            ws += NBUK_MAX * 4;
    int* gcur     = (int*)ws;            ws += NBUK_MAX * 4;
    unsigned int* binned = (unsigned int*)ws;   ws += (size_t)e * 4;
    unsigned short* mqc  = (unsigned short*)ws; ws += (size_t)n * DH * 2;
    float2* m2q   = (float2*)ws;

    const int B = 256;
    const int fill_blocks = (e + FILL_EDGES - 1) / FILL_EDGES;   // 782

    zero_kernel<<<(n + B - 1) / B, B, 0, stream>>>(deg, gcnt, n, nbuk);
    hist_kernel<<<fill_blocks, B, 0, stream>>>(dst, deg, gcnt, e, nbuk);
    dinv_kernel<<<(n + B - 1) / B, B, 0, stream>>>(deg, dinv, n);
    scan_kernel<<<1, B, 0, stream>>>(gcnt, gbase, gcur, nbuk);
    binfill_kernel<<<fill_blocks, B, 0, stream>>>(src, dst, gcur, binned, e, nbuk);
    gemm1_kernel<<<(n + 127) / 128, B, 0, stream>>>(x, W1, dinv, mqc, n);
    agg1_kernel<<<nbuk, B, 0, stream>>>(gbase, gcnt, binned, mqc, dinv, b1, W2, m2q, n);
    agg2_kernel<<<nbuk, B, 0, stream>>>(gbase, gcnt, binned, m2q, dinv, b2, out, n);
}

// Round 6
// 964.236 us; speedup vs baseline: 1.5053x; 1.5053x over previous
//
#include <hip/hip_runtime.h>
#include <hip/hip_bf16.h>

#define DIN 128
#define DH 32
#define DOUT 2
#define NPB 128            // nodes per bucket
#define NPB_SHIFT 7
#define NBUK_MAX 1024      // supports n <= 131072 (17-bit src packing)
#define FILL_EDGES 8192    // edges per binning block (round-4 value; 4096 regressed)
#define CHUNK 2048         // agg1 in-LDS sort chunk

// ---------------------------------------------------------------------------
// workspace (~20.8 MB, budget ~26.8 MB):
//   deg int[n]; dinv float[n]; gcnt/gbase/gcur int[NBUK_MAX]
//   binned uint[E]: (dst&127)<<17 | src, grouped by 128-node bucket
//   mqc bf16[n*32]: dinv-scaled layer-1 messages;  m2q float2[n]
// ---------------------------------------------------------------------------

__device__ inline unsigned short f2bf(float f) {
    unsigned int u = __float_as_uint(f);
    u = (u + 0x7FFFu + ((u >> 16) & 1u)) >> 16;
    return (unsigned short)u;
}
__device__ inline float bf2f(unsigned short b) {
    return __uint_as_float(((unsigned int)b) << 16);
}

__global__ void zero_kernel(int* __restrict__ deg, int n) {
    int i = blockIdx.x * blockDim.x + threadIdx.x;
    if (i < n) deg[i] = 0;
}

// per-node in-degree only (global int atomics; ~32-way avg contention)
__global__ void hist_kernel(const int* __restrict__ dst, int* __restrict__ deg, int e) {
    int i = blockIdx.x * blockDim.x + threadIdx.x;
    if (i < e) atomicAdd(&deg[dst[i]], 1);
}

__global__ void dinv_kernel(const int* __restrict__ deg, float* __restrict__ dinv, int n) {
    int i = blockIdx.x * blockDim.x + threadIdx.x;
    if (i < n) dinv[i] = rsqrtf((float)(deg[i] + 1));
}

// gcnt[b] = sum of deg over the bucket's 128 nodes (block = 128 thr = 1 bucket)
__global__ void bukred_kernel(const int* __restrict__ deg, int* __restrict__ gcnt, int n) {
    __shared__ int s[128];
    int b = blockIdx.x, t = threadIdx.x;
    int r = (b << NPB_SHIFT) + t;
    s[t] = (r < n) ? deg[r] : 0;
    __syncthreads();
    for (int o = 64; o > 0; o >>= 1) {
        if (t < o) s[t] += s[t + o];
        __syncthreads();
    }
    if (t == 0) gcnt[b] = s[0];
}

// single-block exclusive scan of gcnt[nbuk] -> gbase, gcur
__global__ void scan_kernel(const int* __restrict__ gcnt, int* __restrict__ gbase,
                            int* __restrict__ gcur, int nbuk) {
    __shared__ int sd[256];
    int t = threadIdx.x;
    int v[4], s = 0;
#pragma unroll
    for (int k = 0; k < 4; ++k) {
        int i = 4 * t + k;
        v[k] = (i < nbuk) ? gcnt[i] : 0;
        s += v[k];
    }
    sd[t] = s;
    __syncthreads();
    for (int off = 1; off < 256; off <<= 1) {
        int x = (t >= off) ? sd[t - off] : 0;
        __syncthreads();
        sd[t] += x;
        __syncthreads();
    }
    int run = sd[t] - s;
#pragma unroll
    for (int k = 0; k < 4; ++k) {
        int i = 4 * t + k;
        if (i < nbuk) { gbase[i] = run; gcur[i] = run; }
        run += v[k];
    }
}

// LDS counting-sort of 8192 edges by bucket, bulk-append to global regions
__global__ void binfill_kernel(const int* __restrict__ src, const int* __restrict__ dst,
                               int* __restrict__ gcur, unsigned int* __restrict__ binned,
                               int e, int nbuk) {
    __shared__ int cnt[NBUK_MAX];
    __shared__ int pos[NBUK_MAX];
    __shared__ int gb[NBUK_MAX];
    __shared__ unsigned int sorted[FILL_EDGES];
    __shared__ unsigned short aux[FILL_EDGES];
    __shared__ int stmp[256];

    int t = threadIdx.x;
    int e0 = blockIdx.x * FILL_EDGES;
    int m = min(FILL_EDGES, e - e0);

    for (int i = t; i < nbuk; i += 256) cnt[i] = 0;
    __syncthreads();
    for (int i = t; i < m; i += 256) atomicAdd(&cnt[dst[e0 + i] >> NPB_SHIFT], 1);
    __syncthreads();

    int v[4], s = 0;
#pragma unroll
    for (int k = 0; k < 4; ++k) {
        int i = 4 * t + k;
        v[k] = (i < nbuk) ? cnt[i] : 0;
        s += v[k];
    }
    stmp[t] = s;
    __syncthreads();
    for (int off = 1; off < 256; off <<= 1) {
        int x = (t >= off) ? stmp[t - off] : 0;
        __syncthreads();
        stmp[t] += x;
        __syncthreads();
    }
    int run = stmp[t] - s;
#pragma unroll
    for (int k = 0; k < 4; ++k) {
        int i = 4 * t + k;
        if (i < nbuk) pos[i] = run;
        run += v[k];
    }
    __syncthreads();

    for (int i = t; i < m; i += 256) {
        int d = dst[e0 + i];
        int sv = src[e0 + i];
        int b = d >> NPB_SHIFT;
        int r = atomicAdd(&pos[b], 1);
        sorted[r] = ((unsigned int)(d & (NPB - 1)) << 17) | (unsigned int)sv;
        aux[r] = (unsigned short)b;
    }
    __syncthreads();

    for (int b = t; b < nbuk; b += 256) {
        int c = cnt[b];
        gb[b] = c ? atomicAdd(&gcur[b], c) : 0;
    }
    __syncthreads();

    for (int i = t; i < m; i += 256) {
        int b = aux[i];
        int start = pos[b] - cnt[b];
        binned[gb[b] + (i - start)] = sorted[i];
    }
}

// mqc[r][c] = (x[r]·W1[:,c]) * dinv[r], bf16.  128 rows/block,
// thread = (rq 0..31)x(cg 0..7) owning 4 rows x 4 cols outer product.
__global__ void gemm1_kernel(const float* __restrict__ x, const float* __restrict__ W1,
                             const float* __restrict__ dinv,
                             unsigned short* __restrict__ mqc, int n) {
    __shared__ float4 Wl4[DIN * 8];   // 16 KB, [k][cg]
    int t = threadIdx.x;
    for (int i = t; i < DIN * 8; i += 256) Wl4[i] = ((const float4*)W1)[i];
    __syncthreads();

    const int rq = t >> 3, cg = t & 7;
    const int r0 = blockIdx.x * 128 + rq * 4;
    const float4* x4 = (const float4*)x;

    float4 a0 = {0,0,0,0}, a1 = {0,0,0,0}, a2 = {0,0,0,0}, a3 = {0,0,0,0};
    const bool full = (r0 + 3 < n);

#pragma unroll 8
    for (int kk = 0; kk < 32; ++kk) {
        float4 z = {0,0,0,0};
        float4 x0 = z, x1 = z, x2 = z, x3 = z;
        if (full) {
            x0 = x4[(size_t)(r0 + 0) * 32 + kk];
            x1 = x4[(size_t)(r0 + 1) * 32 + kk];
            x2 = x4[(size_t)(r0 + 2) * 32 + kk];
            x3 = x4[(size_t)(r0 + 3) * 32 + kk];
        } else {
            if (r0 + 0 < n) x0 = x4[(size_t)(r0 + 0) * 32 + kk];
            if (r0 + 1 < n) x1 = x4[(size_t)(r0 + 1) * 32 + kk];
            if (r0 + 2 < n) x2 = x4[(size_t)(r0 + 2) * 32 + kk];
            if (r0 + 3 < n) x3 = x4[(size_t)(r0 + 3) * 32 + kk];
        }
        float4 w0 = Wl4[(4 * kk + 0) * 8 + cg];
        float4 w1 = Wl4[(4 * kk + 1) * 8 + cg];
        float4 w2 = Wl4[(4 * kk + 2) * 8 + cg];
        float4 w3 = Wl4[(4 * kk + 3) * 8 + cg];
#define ACC(A, X) \
        A.x += X.x * w0.x + X.y * w1.x + X.z * w2.x + X.w * w3.x; \
        A.y += X.x * w0.y + X.y * w1.y + X.z * w2.y + X.w * w3.y; \
        A.z += X.x * w0.z + X.y * w1.z + X.z * w2.z + X.w * w3.z; \
        A.w += X.x * w0.w + X.y * w1.w + X.z * w2.w + X.w * w3.w;
        ACC(a0, x0) ACC(a1, x1) ACC(a2, x2) ACC(a3, x3)
#undef ACC
    }

#define STORE(I, A) \
    if (r0 + I < n) { \
        float di = dinv[r0 + I]; \
        ushort4 sv; \
        sv.x = f2bf(A.x * di); sv.y = f2bf(A.y * di); \
        sv.z = f2bf(A.z * di); sv.w = f2bf(A.w * di); \
        *(ushort4*)&mqc[(size_t)(r0 + I) * DH + 4 * cg] = sv; \
    }
    STORE(0, a0) STORE(1, a1) STORE(2, a2) STORE(3, a3)
#undef STORE
}

// one block per bucket: chunked in-LDS counting sort by node (int atomics only),
// then REGISTER-accumulated gather: halfwave = 32 lanes = dims, 16 nodes each
// (node j = q*8 + halfwave, q = 0..15).  No fp32 LDS atomics anywhere.
__global__ void agg1_kernel(const int* __restrict__ gbase, const int* __restrict__ gcnt,
                            const int* __restrict__ deg,
                            const unsigned int* __restrict__ binned,
                            const unsigned short* __restrict__ mqc,
                            const float* __restrict__ dinv,
                            const float* __restrict__ b1, const float* __restrict__ W2,
                            float2* __restrict__ m2q, int n) {
    __shared__ unsigned int rawc[CHUNK];     // 8 KB
    __shared__ unsigned int sortedc[CHUNK];  // 8 KB (src only)
    __shared__ int cnt[NPB];
    __shared__ int cur[NPB];
    __shared__ int stmp[256];

    const int t = threadIdx.x;
    const int b = blockIdx.x;
    const int lane = t & 31;
    const int half = t >> 5;    // 0..7
    const int beg = gbase[b];
    const int cntb = gcnt[b];
    const int r0 = b << NPB_SHIFT;

    float acc[16];
#pragma unroll
    for (int q = 0; q < 16; ++q) acc[q] = 0.0f;

    for (int off = 0; off < cntb; off += CHUNK) {
        const int m = min(CHUNK, cntb - off);

        // zero counters
        if (t < NPB) cnt[t] = 0;
        __syncthreads();

        // load + count (int LDS atomics)
        for (int i = t; i < m; i += 256) {
            unsigned int en = binned[beg + off + i];
            rawc[i] = en;
            atomicAdd(&cnt[en >> 17], 1);
        }
        __syncthreads();

        // exclusive scan cnt -> cur (256-wide Hillis-Steele, 128 live)
        int v = (t < NPB) ? cnt[t] : 0;
        stmp[t] = v;
        __syncthreads();
        for (int o = 1; o < 256; o <<= 1) {
            int xx = (t >= o) ? stmp[t - o] : 0;
            __syncthreads();
            stmp[t] += xx;
            __syncthreads();
        }
        if (t < NPB) cur[t] = stmp[t] - v;
        __syncthreads();

        // scatter into node-sorted order (int LDS atomic-return)
        for (int i = t; i < m; i += 256) {
            unsigned int en = rawc[i];
            int p = atomicAdd(&cur[en >> 17], 1);
            sortedc[p] = en & 0x1FFFFu;
        }
        __syncthreads();

        // register-accumulated gather: node j = q*8 + half, lane = dim
#pragma unroll
        for (int q = 0; q < 16; ++q) {
            const int j = q * 8 + half;
            const int e1 = cur[j];          // end (cur advanced to end)
            const int e0 = e1 - cnt[j];
            float a = acc[q];
            for (int base = e0; base < e1; base += 32) {
                int k = e1 - base;
                unsigned int sv = 0;
                if (base + lane < e1) sv = sortedc[base + lane];
                if (k >= 32) {
#pragma unroll
                    for (int u = 0; u < 32; ++u) {
                        int s = __shfl((int)sv, u, 32);
                        a += bf2f(mqc[(size_t)s * DH + lane]);
                    }
                } else {
                    for (int u = 0; u < k; ++u) {
                        int s = __shfl((int)sv, u, 32);
                        a += bf2f(mqc[(size_t)s * DH + lane]);
                    }
                }
            }
            acc[q] = a;
        }
        __syncthreads();   // protect cnt/cur/rawc/sortedc before next chunk
    }

    // epilogue: self message + ReLU + W2 transform
#pragma unroll
    for (int q = 0; q < 16; ++q) {
        const int j = q * 8 + half;
        const int r = r0 + j;
        if (r < n) {
            float di = dinv[r];
            float a = acc[q] + bf2f(mqc[(size_t)r * DH + lane]);
            float h = fmaxf(di * a + b1[lane], 0.0f);
            float p0 = h * W2[lane * DOUT + 0];
            float p1 = h * W2[lane * DOUT + 1];
#pragma unroll
            for (int o = 16; o > 0; o >>= 1) {
                p0 += __shfl_down(p0, o, 32);
                p1 += __shfl_down(p1, o, 32);
            }
            if (lane == 0) m2q[r] = make_float2(di * p0, di * p1);
        }
    }
}

// one block per bucket: layer-2 aggregate + bias (LDS fp32 atomics — only
// 6.4M lane-ops total; controlled test of the 4cyc/lane atomic model)
__global__ void agg2_kernel(const int* __restrict__ gbase, const int* __restrict__ gcnt,
                            const unsigned int* __restrict__ binned,
                            const float2* __restrict__ m2q,
                            const float* __restrict__ dinv, const float* __restrict__ b2,
                            float* __restrict__ out, int n) {
    __shared__ float acc0[NPB], acc1[NPB];
    int t = threadIdx.x;
    int b = blockIdx.x;
    for (int i = t; i < NPB; i += 256) { acc0[i] = 0.f; acc1[i] = 0.f; }
    __syncthreads();

    const int beg = gbase[b];
    const int cntb = gcnt[b];
    for (int i = t; i < cntb; i += 256) {
        unsigned int entry = binned[beg + i];
        int sv = (int)(entry & 0x1FFFFu);
        int dl = (int)(entry >> 17);
        float2 v = m2q[sv];
        atomicAdd(&acc0[dl], v.x);
        atomicAdd(&acc1[dl], v.y);
    }
    __syncthreads();

    int r0 = b << NPB_SHIFT;
    for (int rl = t; rl < NPB; rl += 256) {
        int r = r0 + rl;
        if (r < n) {
            float di = dinv[r];
            float2 self = m2q[r];
            out[(size_t)r * DOUT + 0] = di * (acc0[rl] + self.x) + b2[0];
            out[(size_t)r * DOUT + 1] = di * (acc1[rl] + self.y) + b2[1];
        }
    }
}

extern "C" void kernel_launch(void* const* d_in, const int* in_sizes, int n_in,
                              void* d_out, int out_size, void* d_ws, size_t ws_size,
                              hipStream_t stream) {
    const float* x  = (const float*)d_in[0];
    const int*   ei = (const int*)d_in[1];
    const float* W1 = (const float*)d_in[2];
    const float* b1 = (const float*)d_in[3];
    const float* W2 = (const float*)d_in[4];
    const float* b2 = (const float*)d_in[5];
    float* out = (float*)d_out;

    const int n = in_sizes[0] / DIN;
    const int e = in_sizes[1] / 2;
    const int* src = ei;
    const int* dst = ei + e;
    const int nbuk = (n + NPB - 1) >> NPB_SHIFT;   // 782 for n=100000

    char* ws = (char*)d_ws;
    int* deg      = (int*)ws;            ws += (size_t)n * 4;
    float* dinv   = (float*)ws;          ws += (size_t)n * 4;
    int* gcnt     = (int*)ws;            ws += NBUK_MAX * 4;
    int* gbase    = (int*)ws;            ws += NBUK_MAX * 4;
    int* gcur     = (int*)ws;            ws += NBUK_MAX * 4;
    unsigned int* binned = (unsigned int*)ws;   ws += (size_t)e * 4;
    unsigned short* mqc  = (unsigned short*)ws; ws += (size_t)n * DH * 2;
    float2* m2q   = (float2*)ws;

    const int B = 256;
    const int fill_blocks = (e + FILL_EDGES - 1) / FILL_EDGES;   // 391

    zero_kernel<<<(n + B - 1) / B, B, 0, stream>>>(deg, n);
    hist_kernel<<<(e + B - 1) / B, B, 0, stream>>>(dst, deg, e);
    dinv_kernel<<<(n + B - 1) / B, B, 0, stream>>>(deg, dinv, n);
    bukred_kernel<<<nbuk, 128, 0, stream>>>(deg, gcnt, n);
    scan_kernel<<<1, B, 0, stream>>>(gcnt, gbase, gcur, nbuk);
    binfill_kernel<<<fill_blocks, B, 0, stream>>>(src, dst, gcur, binned, e, nbuk);
    gemm1_kernel<<<(n + 127) / 128, B, 0, stream>>>(x, W1, dinv, mqc, n);
    agg1_kernel<<<nbuk, B, 0, stream>>>(gbase, gcnt, deg, binned, mqc, dinv, b1, W2, m2q, n);
    agg2_kernel<<<nbuk, B, 0, stream>>>(gbase, gcnt, binned, m2q, dinv, b2, out, n);
}

// Round 7
// 555.154 us; speedup vs baseline: 2.6146x; 1.7369x over previous
//
#include <hip/hip_runtime.h>
#include <hip/hip_bf16.h>

#define DIN 128
#define DH 32
#define DOUT 2
#define NPB 128            // nodes per bucket
#define NPB_SHIFT 7
#define NBUK_MAX 1024      // supports n <= 131072 (17-bit src packing)
#define FILL_EDGES 8192    // edges per binning block
#define CHUNK 2048         // agg1 in-LDS sort chunk

// ---------------------------------------------------------------------------
// workspace (~20.8 MB, budget ~26.8 MB):
//   deg int[n]; dinv float[n]; gcnt/gbase/gcur int[NBUK_MAX]
//   binned uint[E]: (dst&127)<<17 | src, grouped by 128-node bucket
//   mqc bf16[n*32]: dinv-scaled layer-1 messages;  m2q float2[n]
// ---------------------------------------------------------------------------

__device__ inline unsigned short f2bf(float f) {
    unsigned int u = __float_as_uint(f);
    u = (u + 0x7FFFu + ((u >> 16) & 1u)) >> 16;
    return (unsigned short)u;
}
__device__ inline float bf2f(unsigned short b) {
    return __uint_as_float(((unsigned int)b) << 16);
}

__global__ void zero_kernel(int* __restrict__ deg, int n) {
    int i = blockIdx.x * blockDim.x + threadIdx.x;
    if (i < n) deg[i] = 0;
}

__global__ void hist_kernel(const int* __restrict__ dst, int* __restrict__ deg, int e) {
    int i = blockIdx.x * blockDim.x + threadIdx.x;
    if (i < e) atomicAdd(&deg[dst[i]], 1);
}

__global__ void dinv_kernel(const int* __restrict__ deg, float* __restrict__ dinv, int n) {
    int i = blockIdx.x * blockDim.x + threadIdx.x;
    if (i < n) dinv[i] = rsqrtf((float)(deg[i] + 1));
}

// gcnt[b] = sum of deg over the bucket's 128 nodes
__global__ void bukred_kernel(const int* __restrict__ deg, int* __restrict__ gcnt, int n) {
    __shared__ int s[128];
    int b = blockIdx.x, t = threadIdx.x;
    int r = (b << NPB_SHIFT) + t;
    s[t] = (r < n) ? deg[r] : 0;
    __syncthreads();
    for (int o = 64; o > 0; o >>= 1) {
        if (t < o) s[t] += s[t + o];
        __syncthreads();
    }
    if (t == 0) gcnt[b] = s[0];
}

// single-block exclusive scan of gcnt[nbuk] -> gbase, gcur
__global__ void scan_kernel(const int* __restrict__ gcnt, int* __restrict__ gbase,
                            int* __restrict__ gcur, int nbuk) {
    __shared__ int sd[256];
    int t = threadIdx.x;
    int v[4], s = 0;
#pragma unroll
    for (int k = 0; k < 4; ++k) {
        int i = 4 * t + k;
        v[k] = (i < nbuk) ? gcnt[i] : 0;
        s += v[k];
    }
    sd[t] = s;
    __syncthreads();
    for (int off = 1; off < 256; off <<= 1) {
        int x = (t >= off) ? sd[t - off] : 0;
        __syncthreads();
        sd[t] += x;
        __syncthreads();
    }
    int run = sd[t] - s;
#pragma unroll
    for (int k = 0; k < 4; ++k) {
        int i = 4 * t + k;
        if (i < nbuk) { gbase[i] = run; gcur[i] = run; }
        run += v[k];
    }
}

// LDS counting-sort of 8192 edges by bucket, bulk-append to global regions
__global__ void binfill_kernel(const int* __restrict__ src, const int* __restrict__ dst,
                               int* __restrict__ gcur, unsigned int* __restrict__ binned,
                               int e, int nbuk) {
    __shared__ int cnt[NBUK_MAX];
    __shared__ int pos[NBUK_MAX];
    __shared__ int gb[NBUK_MAX];
    __shared__ unsigned int sorted[FILL_EDGES];
    __shared__ unsigned short aux[FILL_EDGES];
    __shared__ int stmp[256];

    int t = threadIdx.x;
    int e0 = blockIdx.x * FILL_EDGES;
    int m = min(FILL_EDGES, e - e0);

    for (int i = t; i < nbuk; i += 256) cnt[i] = 0;
    __syncthreads();
    for (int i = t; i < m; i += 256) atomicAdd(&cnt[dst[e0 + i] >> NPB_SHIFT], 1);
    __syncthreads();

    int v[4], s = 0;
#pragma unroll
    for (int k = 0; k < 4; ++k) {
        int i = 4 * t + k;
        v[k] = (i < nbuk) ? cnt[i] : 0;
        s += v[k];
    }
    stmp[t] = s;
    __syncthreads();
    for (int off = 1; off < 256; off <<= 1) {
        int x = (t >= off) ? stmp[t - off] : 0;
        __syncthreads();
        stmp[t] += x;
        __syncthreads();
    }
    int run = stmp[t] - s;
#pragma unroll
    for (int k = 0; k < 4; ++k) {
        int i = 4 * t + k;
        if (i < nbuk) pos[i] = run;
        run += v[k];
    }
    __syncthreads();

    for (int i = t; i < m; i += 256) {
        int d = dst[e0 + i];
        int sv = src[e0 + i];
        int b = d >> NPB_SHIFT;
        int r = atomicAdd(&pos[b], 1);
        sorted[r] = ((unsigned int)(d & (NPB - 1)) << 17) | (unsigned int)sv;
        aux[r] = (unsigned short)b;
    }
    __syncthreads();

    for (int b = t; b < nbuk; b += 256) {
        int c = cnt[b];
        gb[b] = c ? atomicAdd(&gcur[b], c) : 0;
    }
    __syncthreads();

    for (int i = t; i < m; i += 256) {
        int b = aux[i];
        int start = pos[b] - cnt[b];
        binned[gb[b] + (i - start)] = sorted[i];
    }
}

// mqc[r][c] = (x[r]·W1[:,c]) * dinv[r], bf16.  Round-3 proven design:
// 32 rows/block staged in padded LDS; thread = (row, 4 cols); ~no spills.
#define XLD 132   // 132 % 32 == 4 -> padded rows; 33 float4 per row
__global__ void gemm1_kernel(const float* __restrict__ x, const float* __restrict__ W1,
                             const float* __restrict__ dinv,
                             unsigned short* __restrict__ mqc, int n) {
    __shared__ float  Xl[32 * XLD];
    __shared__ float4 Wl4[DIN * 8];

    int t = threadIdx.x;
    for (int i = t; i < DIN * 8; i += 256) Wl4[i] = ((const float4*)W1)[i];

    int rb = blockIdx.x * 32;
    for (int i = t; i < 32 * 32; i += 256) {      // 32 rows x 32 float4
        int rr = i >> 5, c4 = i & 31;
        int gr = rb + rr;
        float4 v = make_float4(0.f, 0.f, 0.f, 0.f);
        if (gr < n) v = ((const float4*)x)[(size_t)gr * 32 + c4];
        ((float4*)Xl)[rr * 33 + c4] = v;
    }
    __syncthreads();

    const int lane = t & 7;        // 4 cols each
    const int row  = t >> 3;       // 0..31
    const float* xrow = &Xl[row * XLD];
    float4 acc = make_float4(0.f, 0.f, 0.f, 0.f);
#pragma unroll
    for (int k = 0; k < DIN; ++k) {
        float xv = xrow[k];
        float4 w = Wl4[k * 8 + lane];
        acc.x += xv * w.x; acc.y += xv * w.y;
        acc.z += xv * w.z; acc.w += xv * w.w;
    }
    int r = rb + row;
    if (r < n) {
        float di = dinv[r];
        ushort4 sv;
        sv.x = f2bf(acc.x * di); sv.y = f2bf(acc.y * di);
        sv.z = f2bf(acc.z * di); sv.w = f2bf(acc.w * di);
        *(ushort4*)&mqc[(size_t)r * DH + 4 * lane] = sv;
    }
}

// one block per bucket: chunked in-LDS counting sort by node (int atomics only),
// then REGISTER-accumulated gather: halfwave = 32 lanes = dims, 16 nodes each.
__global__ void agg1_kernel(const int* __restrict__ gbase, const int* __restrict__ gcnt,
                            const int* __restrict__ deg,
                            const unsigned int* __restrict__ binned,
                            const unsigned short* __restrict__ mqc,
                            const float* __restrict__ dinv,
                            const float* __restrict__ b1, const float* __restrict__ W2,
                            float2* __restrict__ m2q, int n) {
    __shared__ unsigned int rawc[CHUNK];
    __shared__ unsigned int sortedc[CHUNK];
    __shared__ int cnt[NPB];
    __shared__ int cur[NPB];
    __shared__ int stmp[256];

    const int t = threadIdx.x;
    const int b = blockIdx.x;
    const int lane = t & 31;
    const int half = t >> 5;    // 0..7
    const int beg = gbase[b];
    const int cntb = gcnt[b];
    const int r0 = b << NPB_SHIFT;

    float acc[16];
#pragma unroll
    for (int q = 0; q < 16; ++q) acc[q] = 0.0f;

    for (int off = 0; off < cntb; off += CHUNK) {
        const int m = min(CHUNK, cntb - off);

        if (t < NPB) cnt[t] = 0;
        __syncthreads();

        for (int i = t; i < m; i += 256) {
            unsigned int en = binned[beg + off + i];
            rawc[i] = en;
            atomicAdd(&cnt[en >> 17], 1);
        }
        __syncthreads();

        int v = (t < NPB) ? cnt[t] : 0;
        stmp[t] = v;
        __syncthreads();
        for (int o = 1; o < 256; o <<= 1) {
            int xx = (t >= o) ? stmp[t - o] : 0;
            __syncthreads();
            stmp[t] += xx;
            __syncthreads();
        }
        if (t < NPB) cur[t] = stmp[t] - v;
        __syncthreads();

        for (int i = t; i < m; i += 256) {
            unsigned int en = rawc[i];
            int p = atomicAdd(&cur[en >> 17], 1);
            sortedc[p] = en & 0x1FFFFu;
        }
        __syncthreads();

#pragma unroll
        for (int q = 0; q < 16; ++q) {
            const int j = q * 8 + half;
            const int e1 = cur[j];
            const int e0 = e1 - cnt[j];
            float a = acc[q];
            for (int base = e0; base < e1; base += 32) {
                int k = e1 - base;
                unsigned int sv = 0;
                if (base + lane < e1) sv = sortedc[base + lane];
                if (k >= 32) {
#pragma unroll
                    for (int u = 0; u < 32; ++u) {
                        int s = __shfl((int)sv, u, 32);
                        a += bf2f(mqc[(size_t)s * DH + lane]);
                    }
                } else {
                    for (int u = 0; u < k; ++u) {
                        int s = __shfl((int)sv, u, 32);
                        a += bf2f(mqc[(size_t)s * DH + lane]);
                    }
                }
            }
            acc[q] = a;
        }
        __syncthreads();
    }

#pragma unroll
    for (int q = 0; q < 16; ++q) {
        const int j = q * 8 + half;
        const int r = r0 + j;
        if (r < n) {
            float di = dinv[r];
            float a = acc[q] + bf2f(mqc[(size_t)r * DH + lane]);
            float h = fmaxf(di * a + b1[lane], 0.0f);
            float p0 = h * W2[lane * DOUT + 0];
            float p1 = h * W2[lane * DOUT + 1];
#pragma unroll
            for (int o = 16; o > 0; o >>= 1) {
                p0 += __shfl_down(p0, o, 32);
                p1 += __shfl_down(p1, o, 32);
            }
            if (lane == 0) m2q[r] = make_float2(di * p0, di * p1);
        }
    }
}

// one block per bucket: layer-2 aggregate + bias (6.4M LDS fp32 lane-atomics)
__global__ void agg2_kernel(const int* __restrict__ gbase, const int* __restrict__ gcnt,
                            const unsigned int* __restrict__ binned,
                            const float2* __restrict__ m2q,
                            const float* __restrict__ dinv, const float* __restrict__ b2,
                            float* __restrict__ out, int n) {
    __shared__ float acc0[NPB], acc1[NPB];
    int t = threadIdx.x;
    int b = blockIdx.x;
    for (int i = t; i < NPB; i += 256) { acc0[i] = 0.f; acc1[i] = 0.f; }
    __syncthreads();

    const int beg = gbase[b];
    const int cntb = gcnt[b];
    for (int i = t; i < cntb; i += 256) {
        unsigned int entry = binned[beg + i];
        int sv = (int)(entry & 0x1FFFFu);
        int dl = (int)(entry >> 17);
        float2 v = m2q[sv];
        atomicAdd(&acc0[dl], v.x);
        atomicAdd(&acc1[dl], v.y);
    }
    __syncthreads();

    int r0 = b << NPB_SHIFT;
    for (int rl = t; rl < NPB; rl += 256) {
        int r = r0 + rl;
        if (r < n) {
            float di = dinv[r];
            float2 self = m2q[r];
            out[(size_t)r * DOUT + 0] = di * (acc0[rl] + self.x) + b2[0];
            out[(size_t)r * DOUT + 1] = di * (acc1[rl] + self.y) + b2[1];
        }
    }
}

extern "C" void kernel_launch(void* const* d_in, const int* in_sizes, int n_in,
                              void* d_out, int out_size, void* d_ws, size_t ws_size,
                              hipStream_t stream) {
    const float* x  = (const float*)d_in[0];
    const int*   ei = (const int*)d_in[1];
    const float* W1 = (const float*)d_in[2];
    const float* b1 = (const float*)d_in[3];
    const float* W2 = (const float*)d_in[4];
    const float* b2 = (const float*)d_in[5];
    float* out = (float*)d_out;

    const int n = in_sizes[0] / DIN;
    const int e = in_sizes[1] / 2;
    const int* src = ei;
    const int* dst = ei + e;
    const int nbuk = (n + NPB - 1) >> NPB_SHIFT;   // 782 for n=100000

    char* ws = (char*)d_ws;
    int* deg      = (int*)ws;            ws += (size_t)n * 4;
    float* dinv   = (float*)ws;          ws += (size_t)n * 4;
    int* gcnt     = (int*)ws;            ws += NBUK_MAX * 4;
    int* gbase    = (int*)ws;            ws += NBUK_MAX * 4;
    int* gcur     = (int*)ws;            ws += NBUK_MAX * 4;
    unsigned int* binned = (unsigned int*)ws;   ws += (size_t)e * 4;
    unsigned short* mqc  = (unsigned short*)ws; ws += (size_t)n * DH * 2;
    float2* m2q   = (float2*)ws;

    const int B = 256;
    const int fill_blocks = (e + FILL_EDGES - 1) / FILL_EDGES;   // 391

    zero_kernel<<<(n + B - 1) / B, B, 0, stream>>>(deg, n);
    hist_kernel<<<(e + B - 1) / B, B, 0, stream>>>(dst, deg, e);
    dinv_kernel<<<(n + B - 1) / B, B, 0, stream>>>(deg, dinv, n);
    bukred_kernel<<<nbuk, 128, 0, stream>>>(deg, gcnt, n);
    scan_kernel<<<1, B, 0, stream>>>(gcnt, gbase, gcur, nbuk);
    binfill_kernel<<<fill_blocks, B, 0, stream>>>(src, dst, gcur, binned, e, nbuk);
    gemm1_kernel<<<(n + 31) / 32, B, 0, stream>>>(x, W1, dinv, mqc, n);
    agg1_kernel<<<nbuk, B, 0, stream>>>(gbase, gcnt, deg, binned, mqc, dinv, b1, W2, m2q, n);
    agg2_kernel<<<nbuk, B, 0, stream>>>(gbase, gcnt, binned, m2q, dinv, b2, out, n);
}

// Round 8
// 416.170 us; speedup vs baseline: 3.4877x; 1.3340x over previous
//
#include <hip/hip_runtime.h>
#include <hip/hip_bf16.h>

#define DIN 128
#define DH 32
#define DOUT 2
#define NPB 128            // nodes per bucket
#define NPB_SHIFT 7
#define NBUK_MAX 1024      // supports n <= 131072 (17-bit src packing)
#define FILL_EDGES 8192    // edges per binning block
#define CHUNK 2048         // agg1 in-LDS sort chunk

// ---------------------------------------------------------------------------
// workspace (~20.8 MB, budget ~26.8 MB):
//   deg int[n]; dinv float[n]; gcnt/gbase/gcur int[NBUK_MAX]
//   binned uint[E]: (dst&127)<<17 | src, grouped by 128-node bucket
//   mqc bf16[n*32]: dinv-scaled layer-1 messages;  m2q float2[n]
// ---------------------------------------------------------------------------

__device__ inline unsigned short f2bf(float f) {
    unsigned int u = __float_as_uint(f);
    u = (u + 0x7FFFu + ((u >> 16) & 1u)) >> 16;
    return (unsigned short)u;
}
__device__ inline float bf2f(unsigned short b) {
    return __uint_as_float(((unsigned int)b) << 16);
}

__global__ void zero_kernel(int* __restrict__ deg, int n) {
    int i = blockIdx.x * blockDim.x + threadIdx.x;
    if (i < n) deg[i] = 0;
}

__global__ void hist_kernel(const int* __restrict__ dst, int* __restrict__ deg, int e) {
    int i = blockIdx.x * blockDim.x + threadIdx.x;
    if (i < e) atomicAdd(&deg[dst[i]], 1);
}

__global__ void dinv_kernel(const int* __restrict__ deg, float* __restrict__ dinv, int n) {
    int i = blockIdx.x * blockDim.x + threadIdx.x;
    if (i < n) dinv[i] = rsqrtf((float)(deg[i] + 1));
}

// gcnt[b] = sum of deg over the bucket's 128 nodes
__global__ void bukred_kernel(const int* __restrict__ deg, int* __restrict__ gcnt, int n) {
    __shared__ int s[128];
    int b = blockIdx.x, t = threadIdx.x;
    int r = (b << NPB_SHIFT) + t;
    s[t] = (r < n) ? deg[r] : 0;
    __syncthreads();
    for (int o = 64; o > 0; o >>= 1) {
        if (t < o) s[t] += s[t + o];
        __syncthreads();
    }
    if (t == 0) gcnt[b] = s[0];
}

// single-block exclusive scan of gcnt[nbuk] -> gbase, gcur
__global__ void scan_kernel(const int* __restrict__ gcnt, int* __restrict__ gbase,
                            int* __restrict__ gcur, int nbuk) {
    __shared__ int sd[256];
    int t = threadIdx.x;
    int v[4], s = 0;
#pragma unroll
    for (int k = 0; k < 4; ++k) {
        int i = 4 * t + k;
        v[k] = (i < nbuk) ? gcnt[i] : 0;
        s += v[k];
    }
    sd[t] = s;
    __syncthreads();
    for (int off = 1; off < 256; off <<= 1) {
        int x = (t >= off) ? sd[t - off] : 0;
        __syncthreads();
        sd[t] += x;
        __syncthreads();
    }
    int run = sd[t] - s;
#pragma unroll
    for (int k = 0; k < 4; ++k) {
        int i = 4 * t + k;
        if (i < nbuk) { gbase[i] = run; gcur[i] = run; }
        run += v[k];
    }
}

// LDS counting-sort of 8192 edges by bucket, bulk-append to global regions
__global__ void binfill_kernel(const int* __restrict__ src, const int* __restrict__ dst,
                               int* __restrict__ gcur, unsigned int* __restrict__ binned,
                               int e, int nbuk) {
    __shared__ int cnt[NBUK_MAX];
    __shared__ int pos[NBUK_MAX];
    __shared__ int gb[NBUK_MAX];
    __shared__ unsigned int sorted[FILL_EDGES];
    __shared__ unsigned short aux[FILL_EDGES];
    __shared__ int stmp[256];

    int t = threadIdx.x;
    int e0 = blockIdx.x * FILL_EDGES;
    int m = min(FILL_EDGES, e - e0);

    for (int i = t; i < nbuk; i += 256) cnt[i] = 0;
    __syncthreads();
    for (int i = t; i < m; i += 256) atomicAdd(&cnt[dst[e0 + i] >> NPB_SHIFT], 1);
    __syncthreads();

    int v[4], s = 0;
#pragma unroll
    for (int k = 0; k < 4; ++k) {
        int i = 4 * t + k;
        v[k] = (i < nbuk) ? cnt[i] : 0;
        s += v[k];
    }
    stmp[t] = s;
    __syncthreads();
    for (int off = 1; off < 256; off <<= 1) {
        int x = (t >= off) ? stmp[t - off] : 0;
        __syncthreads();
        stmp[t] += x;
        __syncthreads();
    }
    int run = stmp[t] - s;
#pragma unroll
    for (int k = 0; k < 4; ++k) {
        int i = 4 * t + k;
        if (i < nbuk) pos[i] = run;
        run += v[k];
    }
    __syncthreads();

    for (int i = t; i < m; i += 256) {
        int d = dst[e0 + i];
        int sv = src[e0 + i];
        int b = d >> NPB_SHIFT;
        int r = atomicAdd(&pos[b], 1);
        sorted[r] = ((unsigned int)(d & (NPB - 1)) << 17) | (unsigned int)sv;
        aux[r] = (unsigned short)b;
    }
    __syncthreads();

    for (int b = t; b < nbuk; b += 256) {
        int c = cnt[b];
        gb[b] = c ? atomicAdd(&gcur[b], c) : 0;
    }
    __syncthreads();

    for (int i = t; i < m; i += 256) {
        int b = aux[i];
        int start = pos[b] - cnt[b];
        binned[gb[b] + (i - start)] = sorted[i];
    }
}

// mqc[r][c] = (x[r]·W1[:,c]) * dinv[r], bf16.  32 rows/block staged in
// padded LDS; thread = (row, 4 cols); register-lean, no spills.
#define XLD 132
__global__ void gemm1_kernel(const float* __restrict__ x, const float* __restrict__ W1,
                             const float* __restrict__ dinv,
                             unsigned short* __restrict__ mqc, int n) {
    __shared__ float  Xl[32 * XLD];
    __shared__ float4 Wl4[DIN * 8];

    int t = threadIdx.x;
    for (int i = t; i < DIN * 8; i += 256) Wl4[i] = ((const float4*)W1)[i];

    int rb = blockIdx.x * 32;
    for (int i = t; i < 32 * 32; i += 256) {
        int rr = i >> 5, c4 = i & 31;
        int gr = rb + rr;
        float4 v = make_float4(0.f, 0.f, 0.f, 0.f);
        if (gr < n) v = ((const float4*)x)[(size_t)gr * 32 + c4];
        ((float4*)Xl)[rr * 33 + c4] = v;
    }
    __syncthreads();

    const int lane = t & 7;
    const int row  = t >> 3;
    const float* xrow = &Xl[row * XLD];
    float4 acc = make_float4(0.f, 0.f, 0.f, 0.f);
#pragma unroll
    for (int k = 0; k < DIN; ++k) {
        float xv = xrow[k];
        float4 w = Wl4[k * 8 + lane];
        acc.x += xv * w.x; acc.y += xv * w.y;
        acc.z += xv * w.z; acc.w += xv * w.w;
    }
    int r = rb + row;
    if (r < n) {
        float di = dinv[r];
        ushort4 sv;
        sv.x = f2bf(acc.x * di); sv.y = f2bf(acc.y * di);
        sv.z = f2bf(acc.z * di); sv.w = f2bf(acc.w * di);
        *(ushort4*)&mqc[(size_t)r * DH + 4 * lane] = sv;
    }
}

// one block per bucket: chunked in-LDS counting sort by node (int atomics),
// then TRANSPOSED register gather: u-step outer, 16 node-accumulators inner
// (fully unrolled) -> 16 independent loads in flight per step.
__global__ void agg1_kernel(const int* __restrict__ gbase, const int* __restrict__ gcnt,
                            const unsigned int* __restrict__ binned,
                            const unsigned short* __restrict__ mqc,
                            const float* __restrict__ dinv,
                            const float* __restrict__ b1, const float* __restrict__ W2,
                            float2* __restrict__ m2q, int n) {
    __shared__ unsigned int rawc[CHUNK];
    __shared__ unsigned int sortedc[CHUNK];
    __shared__ int cnt[NPB];
    __shared__ int cur[NPB];
    __shared__ int stmp[256];

    const int t = threadIdx.x;
    const int b = blockIdx.x;
    const int lane = t & 31;
    const int half = t >> 5;    // 0..7
    const int beg = gbase[b];
    const int cntb = gcnt[b];
    const int r0 = b << NPB_SHIFT;

    float acc[16];
#pragma unroll
    for (int q = 0; q < 16; ++q) acc[q] = 0.0f;

    for (int off = 0; off < cntb; off += CHUNK) {
        const int m = min(CHUNK, cntb - off);

        if (t < NPB) cnt[t] = 0;
        __syncthreads();

        for (int i = t; i < m; i += 256) {
            unsigned int en = binned[beg + off + i];
            rawc[i] = en;
            atomicAdd(&cnt[en >> 17], 1);
        }
        __syncthreads();

        int v = (t < NPB) ? cnt[t] : 0;
        stmp[t] = v;
        __syncthreads();
        for (int o = 1; o < 256; o <<= 1) {
            int xx = (t >= o) ? stmp[t - o] : 0;
            __syncthreads();
            stmp[t] += xx;
            __syncthreads();
        }
        if (t < NPB) cur[t] = stmp[t] - v;
        __syncthreads();

        for (int i = t; i < m; i += 256) {
            unsigned int en = rawc[i];
            int p = atomicAdd(&cur[en >> 17], 1);
            sortedc[p] = en & 0x1FFFFu;
        }
        __syncthreads();

        // transposed gather: per u-step, 16 independent node loads in flight
        int e0q[16], kq[16];
        int maxk = 0;
#pragma unroll
        for (int q = 0; q < 16; ++q) {
            int j = q * 8 + half;
            int c = cnt[j];
            e0q[q] = cur[j] - c;   // cur advanced to end during scatter
            kq[q] = c;
            maxk = max(maxk, c);
        }
        for (int u = 0; u < maxk; ++u) {
#pragma unroll
            for (int q = 0; q < 16; ++q) {
                int idx = min(e0q[q] + u, m - 1);       // always-valid LDS slot
                int s = (int)sortedc[idx];              // broadcast read
                float val = bf2f(mqc[(size_t)s * DH + lane]);
                acc[q] += (u < kq[q]) ? val : 0.0f;     // predicated add
            }
        }
        __syncthreads();
    }

    // epilogue: self message + ReLU + W2 transform
#pragma unroll
    for (int q = 0; q < 16; ++q) {
        const int j = q * 8 + half;
        const int r = r0 + j;
        if (r < n) {
            float di = dinv[r];
            float a = acc[q] + bf2f(mqc[(size_t)r * DH + lane]);
            float h = fmaxf(di * a + b1[lane], 0.0f);
            float p0 = h * W2[lane * DOUT + 0];
            float p1 = h * W2[lane * DOUT + 1];
#pragma unroll
            for (int o = 16; o > 0; o >>= 1) {
                p0 += __shfl_down(p0, o, 32);
                p1 += __shfl_down(p1, o, 32);
            }
            if (lane == 0) m2q[r] = make_float2(di * p0, di * p1);
        }
    }
}

// one block per bucket: layer-2 aggregate + bias (6.4M LDS fp32 lane-atomics)
__global__ void agg2_kernel(const int* __restrict__ gbase, const int* __restrict__ gcnt,
                            const unsigned int* __restrict__ binned,
                            const float2* __restrict__ m2q,
                            const float* __restrict__ dinv, const float* __restrict__ b2,
                            float* __restrict__ out, int n) {
    __shared__ float acc0[NPB], acc1[NPB];
    int t = threadIdx.x;
    int b = blockIdx.x;
    for (int i = t; i < NPB; i += 256) { acc0[i] = 0.f; acc1[i] = 0.f; }
    __syncthreads();

    const int beg = gbase[b];
    const int cntb = gcnt[b];
    for (int i = t; i < cntb; i += 256) {
        unsigned int entry = binned[beg + i];
        int sv = (int)(entry & 0x1FFFFu);
        int dl = (int)(entry >> 17);
        float2 v = m2q[sv];
        atomicAdd(&acc0[dl], v.x);
        atomicAdd(&acc1[dl], v.y);
    }
    __syncthreads();

    int r0 = b << NPB_SHIFT;
    for (int rl = t; rl < NPB; rl += 256) {
        int r = r0 + rl;
        if (r < n) {
            float di = dinv[r];
            float2 self = m2q[r];
            out[(size_t)r * DOUT + 0] = di * (acc0[rl] + self.x) + b2[0];
            out[(size_t)r * DOUT + 1] = di * (acc1[rl] + self.y) + b2[1];
        }
    }
}

extern "C" void kernel_launch(void* const* d_in, const int* in_sizes, int n_in,
                              void* d_out, int out_size, void* d_ws, size_t ws_size,
                              hipStream_t stream) {
    const float* x  = (const float*)d_in[0];
    const int*   ei = (const int*)d_in[1];
    const float* W1 = (const float*)d_in[2];
    const float* b1 = (const float*)d_in[3];
    const float* W2 = (const float*)d_in[4];
    const float* b2 = (const float*)d_in[5];
    float* out = (float*)d_out;

    const int n = in_sizes[0] / DIN;
    const int e = in_sizes[1] / 2;
    const int* src = ei;
    const int* dst = ei + e;
    const int nbuk = (n + NPB - 1) >> NPB_SHIFT;   // 782 for n=100000

    char* ws = (char*)d_ws;
    int* deg      = (int*)ws;            ws += (size_t)n * 4;
    float* dinv   = (float*)ws;          ws += (size_t)n * 4;
    int* gcnt     = (int*)ws;            ws += NBUK_MAX * 4;
    int* gbase    = (int*)ws;            ws += NBUK_MAX * 4;
    int* gcur     = (int*)ws;            ws += NBUK_MAX * 4;
    unsigned int* binned = (unsigned int*)ws;   ws += (size_t)e * 4;
    unsigned short* mqc  = (unsigned short*)ws; ws += (size_t)n * DH * 2;
    float2* m2q   = (float2*)ws;

    const int B = 256;
    const int fill_blocks = (e + FILL_EDGES - 1) / FILL_EDGES;   // 391

    zero_kernel<<<(n + B - 1) / B, B, 0, stream>>>(deg, n);
    hist_kernel<<<(e + B - 1) / B, B, 0, stream>>>(dst, deg, e);
    dinv_kernel<<<(n + B - 1) / B, B, 0, stream>>>(deg, dinv, n);
    bukred_kernel<<<nbuk, 128, 0, stream>>>(deg, gcnt, n);
    scan_kernel<<<1, B, 0, stream>>>(gcnt, gbase, gcur, nbuk);
    binfill_kernel<<<fill_blocks, B, 0, stream>>>(src, dst, gcur, binned, e, nbuk);
    gemm1_kernel<<<(n + 31) / 32, B, 0, stream>>>(x, W1, dinv, mqc, n);
    agg1_kernel<<<nbuk, B, 0, stream>>>(gbase, gcnt, binned, mqc, dinv, b1, W2, m2q, n);
    agg2_kernel<<<nbuk, B, 0, stream>>>(gbase, gcnt, binned, m2q, dinv, b2, out, n);
}

// Round 9
// 302.545 us; speedup vs baseline: 4.7976x; 1.3756x over previous
//
#include <hip/hip_runtime.h>
#include <hip/hip_bf16.h>

#define DIN 128
#define DH 32
#define DOUT 2
#define NPB 128            // nodes per bucket
#define NPB_SHIFT 7
#define NBUK_MAX 1024      // supports n <= 131072 (17-bit src packing)
#define FILL_EDGES 8192    // edges per binning block
#define CHUNK 2048         // agg1 in-LDS sort chunk

// ---------------------------------------------------------------------------
// workspace (~20.5 MB, budget ~26.8 MB):
//   dinv float[n]; gcnt/gbase/gcur int[NBUK_MAX]
//   binned uint[E]: (dst&127)<<17 | src, grouped by 128-node bucket
//   mqc bf16[n*32]: dinv-scaled layer-1 messages;  m2q float2[n]
// No global per-node degree array: degree is recovered from binned per bucket.
// ---------------------------------------------------------------------------

__device__ inline unsigned short f2bf(float f) {
    unsigned int u = __float_as_uint(f);
    u = (u + 0x7FFFu + ((u >> 16) & 1u)) >> 16;
    return (unsigned short)u;
}
__device__ inline float bf2f(unsigned short b) {
    return __uint_as_float(((unsigned int)b) << 16);
}

__global__ void zero_gcnt_kernel(int* __restrict__ gcnt, int nbuk) {
    int i = blockIdx.x * blockDim.x + threadIdx.x;
    if (i < nbuk) gcnt[i] = 0;
}

// bucket-level histogram, LDS-staged (no per-node global atomics)
__global__ void bukhist_kernel(const int* __restrict__ dst, int* __restrict__ gcnt,
                               int e, int nbuk) {
    __shared__ int lcnt[NBUK_MAX];
    int t = threadIdx.x;
    for (int i = t; i < nbuk; i += 256) lcnt[i] = 0;
    __syncthreads();
    int e0 = blockIdx.x * FILL_EDGES;
    int m = min(FILL_EDGES, e - e0);
    for (int i = t; i < m; i += 256) atomicAdd(&lcnt[dst[e0 + i] >> NPB_SHIFT], 1);
    __syncthreads();
    for (int i = t; i < nbuk; i += 256)
        if (lcnt[i]) atomicAdd(&gcnt[i], lcnt[i]);
}

// single-block exclusive scan of gcnt[nbuk] -> gbase, gcur
__global__ void scan_kernel(const int* __restrict__ gcnt, int* __restrict__ gbase,
                            int* __restrict__ gcur, int nbuk) {
    __shared__ int sd[256];
    int t = threadIdx.x;
    int v[4], s = 0;
#pragma unroll
    for (int k = 0; k < 4; ++k) {
        int i = 4 * t + k;
        v[k] = (i < nbuk) ? gcnt[i] : 0;
        s += v[k];
    }
    sd[t] = s;
    __syncthreads();
    for (int off = 1; off < 256; off <<= 1) {
        int x = (t >= off) ? sd[t - off] : 0;
        __syncthreads();
        sd[t] += x;
        __syncthreads();
    }
    int run = sd[t] - s;
#pragma unroll
    for (int k = 0; k < 4; ++k) {
        int i = 4 * t + k;
        if (i < nbuk) { gbase[i] = run; gcur[i] = run; }
        run += v[k];
    }
}

// LDS counting-sort of 8192 edges by bucket, bulk-append to global regions
__global__ void binfill_kernel(const int* __restrict__ src, const int* __restrict__ dst,
                               int* __restrict__ gcur, unsigned int* __restrict__ binned,
                               int e, int nbuk) {
    __shared__ int cnt[NBUK_MAX];
    __shared__ int pos[NBUK_MAX];
    __shared__ int gb[NBUK_MAX];
    __shared__ unsigned int sorted[FILL_EDGES];
    __shared__ unsigned short aux[FILL_EDGES];
    __shared__ int stmp[256];

    int t = threadIdx.x;
    int e0 = blockIdx.x * FILL_EDGES;
    int m = min(FILL_EDGES, e - e0);

    for (int i = t; i < nbuk; i += 256) cnt[i] = 0;
    __syncthreads();
    for (int i = t; i < m; i += 256) atomicAdd(&cnt[dst[e0 + i] >> NPB_SHIFT], 1);
    __syncthreads();

    int v[4], s = 0;
#pragma unroll
    for (int k = 0; k < 4; ++k) {
        int i = 4 * t + k;
        v[k] = (i < nbuk) ? cnt[i] : 0;
        s += v[k];
    }
    stmp[t] = s;
    __syncthreads();
    for (int off = 1; off < 256; off <<= 1) {
        int x = (t >= off) ? stmp[t - off] : 0;
        __syncthreads();
        stmp[t] += x;
        __syncthreads();
    }
    int run = stmp[t] - s;
#pragma unroll
    for (int k = 0; k < 4; ++k) {
        int i = 4 * t + k;
        if (i < nbuk) pos[i] = run;
        run += v[k];
    }
    __syncthreads();

    for (int i = t; i < m; i += 256) {
        int d = dst[e0 + i];
        int sv = src[e0 + i];
        int b = d >> NPB_SHIFT;
        int r = atomicAdd(&pos[b], 1);
        sorted[r] = ((unsigned int)(d & (NPB - 1)) << 17) | (unsigned int)sv;
        aux[r] = (unsigned short)b;
    }
    __syncthreads();

    for (int b = t; b < nbuk; b += 256) {
        int c = cnt[b];
        gb[b] = c ? atomicAdd(&gcur[b], c) : 0;
    }
    __syncthreads();

    for (int i = t; i < m; i += 256) {
        int b = aux[i];
        int start = pos[b] - cnt[b];
        binned[gb[b] + (i - start)] = sorted[i];
    }
}

// per-bucket node degree from binned (LDS int atomics) -> dinv = rsqrt(deg+1)
__global__ void bdinv_kernel(const int* __restrict__ gbase, const int* __restrict__ gcnt,
                             const unsigned int* __restrict__ binned,
                             float* __restrict__ dinv, int n) {
    __shared__ int cnt[NPB];
    int t = threadIdx.x;
    int b = blockIdx.x;
    if (t < NPB) cnt[t] = 0;
    __syncthreads();
    const int beg = gbase[b];
    const int cntb = gcnt[b];
    for (int i = t; i < cntb; i += 256) atomicAdd(&cnt[binned[beg + i] >> 17], 1);
    __syncthreads();
    if (t < NPB) {
        int r = (b << NPB_SHIFT) + t;
        if (r < n) dinv[r] = rsqrtf((float)(cnt[t] + 1));
    }
}

// mqc[r][c] = (x[r]·W1[:,c]) * dinv[r], bf16.  32 rows/block staged in
// padded LDS; thread = (row, 4 cols); register-lean, no spills.
#define XLD 132
__global__ void gemm1_kernel(const float* __restrict__ x, const float* __restrict__ W1,
                             const float* __restrict__ dinv,
                             unsigned short* __restrict__ mqc, int n) {
    __shared__ float  Xl[32 * XLD];
    __shared__ float4 Wl4[DIN * 8];

    int t = threadIdx.x;
    for (int i = t; i < DIN * 8; i += 256) Wl4[i] = ((const float4*)W1)[i];

    int rb = blockIdx.x * 32;
    for (int i = t; i < 32 * 32; i += 256) {
        int rr = i >> 5, c4 = i & 31;
        int gr = rb + rr;
        float4 v = make_float4(0.f, 0.f, 0.f, 0.f);
        if (gr < n) v = ((const float4*)x)[(size_t)gr * 32 + c4];
        ((float4*)Xl)[rr * 33 + c4] = v;
    }
    __syncthreads();

    const int lane = t & 7;
    const int row  = t >> 3;
    const float* xrow = &Xl[row * XLD];
    float4 acc = make_float4(0.f, 0.f, 0.f, 0.f);
#pragma unroll
    for (int k = 0; k < DIN; ++k) {
        float xv = xrow[k];
        float4 w = Wl4[k * 8 + lane];
        acc.x += xv * w.x; acc.y += xv * w.y;
        acc.z += xv * w.z; acc.w += xv * w.w;
    }
    int r = rb + row;
    if (r < n) {
        float di = dinv[r];
        ushort4 sv;
        sv.x = f2bf(acc.x * di); sv.y = f2bf(acc.y * di);
        sv.z = f2bf(acc.z * di); sv.w = f2bf(acc.w * di);
        *(ushort4*)&mqc[(size_t)r * DH + 4 * lane] = sv;
    }
}

// one block per bucket: chunked in-LDS counting sort by node (int atomics),
// then TRANSPOSED register gather: u-step outer, 16 node-accumulators inner.
__global__ void agg1_kernel(const int* __restrict__ gbase, const int* __restrict__ gcnt,
                            const unsigned int* __restrict__ binned,
                            const unsigned short* __restrict__ mqc,
                            const float* __restrict__ dinv,
                            const float* __restrict__ b1, const float* __restrict__ W2,
                            float2* __restrict__ m2q, int n) {
    __shared__ unsigned int rawc[CHUNK];
    __shared__ unsigned int sortedc[CHUNK];
    __shared__ int cnt[NPB];
    __shared__ int cur[NPB];
    __shared__ int stmp[256];

    const int t = threadIdx.x;
    const int b = blockIdx.x;
    const int lane = t & 31;
    const int half = t >> 5;    // 0..7
    const int beg = gbase[b];
    const int cntb = gcnt[b];
    const int r0 = b << NPB_SHIFT;

    float acc[16];
#pragma unroll
    for (int q = 0; q < 16; ++q) acc[q] = 0.0f;

    for (int off = 0; off < cntb; off += CHUNK) {
        const int m = min(CHUNK, cntb - off);

        if (t < NPB) cnt[t] = 0;
        __syncthreads();

        for (int i = t; i < m; i += 256) {
            unsigned int en = binned[beg + off + i];
            rawc[i] = en;
            atomicAdd(&cnt[en >> 17], 1);
        }
        __syncthreads();

        int v = (t < NPB) ? cnt[t] : 0;
        stmp[t] = v;
        __syncthreads();
        for (int o = 1; o < 256; o <<= 1) {
            int xx = (t >= o) ? stmp[t - o] : 0;
            __syncthreads();
            stmp[t] += xx;
            __syncthreads();
        }
        if (t < NPB) cur[t] = stmp[t] - v;
        __syncthreads();

        for (int i = t; i < m; i += 256) {
            unsigned int en = rawc[i];
            int p = atomicAdd(&cur[en >> 17], 1);
            sortedc[p] = en & 0x1FFFFu;
        }
        __syncthreads();

        int e0q[16], kq[16];
        int maxk = 0;
#pragma unroll
        for (int q = 0; q < 16; ++q) {
            int j = q * 8 + half;
            int c = cnt[j];
            e0q[q] = cur[j] - c;
            kq[q] = c;
            maxk = max(maxk, c);
        }
        for (int u = 0; u < maxk; ++u) {
#pragma unroll
            for (int q = 0; q < 16; ++q) {
                int idx = min(e0q[q] + u, m - 1);
                int s = (int)sortedc[idx];
                float val = bf2f(mqc[(size_t)s * DH + lane]);
                acc[q] += (u < kq[q]) ? val : 0.0f;
            }
        }
        __syncthreads();
    }

#pragma unroll
    for (int q = 0; q < 16; ++q) {
        const int j = q * 8 + half;
        const int r = r0 + j;
        if (r < n) {
            float di = dinv[r];
            float a = acc[q] + bf2f(mqc[(size_t)r * DH + lane]);
            float h = fmaxf(di * a + b1[lane], 0.0f);
            float p0 = h * W2[lane * DOUT + 0];
            float p1 = h * W2[lane * DOUT + 1];
#pragma unroll
            for (int o = 16; o > 0; o >>= 1) {
                p0 += __shfl_down(p0, o, 32);
                p1 += __shfl_down(p1, o, 32);
            }
            if (lane == 0) m2q[r] = make_float2(di * p0, di * p1);
        }
    }
}

// one block per bucket: layer-2 aggregate + bias
__global__ void agg2_kernel(const int* __restrict__ gbase, const int* __restrict__ gcnt,
                            const unsigned int* __restrict__ binned,
                            const float2* __restrict__ m2q,
                            const float* __restrict__ dinv, const float* __restrict__ b2,
                            float* __restrict__ out, int n) {
    __shared__ float acc0[NPB], acc1[NPB];
    int t = threadIdx.x;
    int b = blockIdx.x;
    for (int i = t; i < NPB; i += 256) { acc0[i] = 0.f; acc1[i] = 0.f; }
    __syncthreads();

    const int beg = gbase[b];
    const int cntb = gcnt[b];
    for (int i = t; i < cntb; i += 256) {
        unsigned int entry = binned[beg + i];
        int sv = (int)(entry & 0x1FFFFu);
        int dl = (int)(entry >> 17);
        float2 v = m2q[sv];
        atomicAdd(&acc0[dl], v.x);
        atomicAdd(&acc1[dl], v.y);
    }
    __syncthreads();

    int r0 = b << NPB_SHIFT;
    for (int rl = t; rl < NPB; rl += 256) {
        int r = r0 + rl;
        if (r < n) {
            float di = dinv[r];
            float2 self = m2q[r];
            out[(size_t)r * DOUT + 0] = di * (acc0[rl] + self.x) + b2[0];
            out[(size_t)r * DOUT + 1] = di * (acc1[rl] + self.y) + b2[1];
        }
    }
}

extern "C" void kernel_launch(void* const* d_in, const int* in_sizes, int n_in,
                              void* d_out, int out_size, void* d_ws, size_t ws_size,
                              hipStream_t stream) {
    const float* x  = (const float*)d_in[0];
    const int*   ei = (const int*)d_in[1];
    const float* W1 = (const float*)d_in[2];
    const float* b1 = (const float*)d_in[3];
    const float* W2 = (const float*)d_in[4];
    const float* b2 = (const float*)d_in[5];
    float* out = (float*)d_out;

    const int n = in_sizes[0] / DIN;
    const int e = in_sizes[1] / 2;
    const int* src = ei;
    const int* dst = ei + e;
    const int nbuk = (n + NPB - 1) >> NPB_SHIFT;   // 782 for n=100000

    char* ws = (char*)d_ws;
    float* dinv   = (float*)ws;          ws += (size_t)n * 4;
    int* gcnt     = (int*)ws;            ws += NBUK_MAX * 4;
    int* gbase    = (int*)ws;            ws += NBUK_MAX * 4;
    int* gcur     = (int*)ws;            ws += NBUK_MAX * 4;
    unsigned int* binned = (unsigned int*)ws;   ws += (size_t)e * 4;
    unsigned short* mqc  = (unsigned short*)ws; ws += (size_t)n * DH * 2;
    float2* m2q   = (float2*)ws;

    const int B = 256;
    const int fill_blocks = (e + FILL_EDGES - 1) / FILL_EDGES;   // 391

    zero_gcnt_kernel<<<(nbuk + B - 1) / B, B, 0, stream>>>(gcnt, nbuk);
    bukhist_kernel<<<fill_blocks, B, 0, stream>>>(dst, gcnt, e, nbuk);
    scan_kernel<<<1, B, 0, stream>>>(gcnt, gbase, gcur, nbuk);
    binfill_kernel<<<fill_blocks, B, 0, stream>>>(src, dst, gcur, binned, e, nbuk);
    bdinv_kernel<<<nbuk, B, 0, stream>>>(gbase, gcnt, binned, dinv, n);
    gemm1_kernel<<<(n + 31) / 32, B, 0, stream>>>(x, W1, dinv, mqc, n);
    agg1_kernel<<<nbuk, B, 0, stream>>>(gbase, gcnt, binned, mqc, dinv, b1, W2, m2q, n);
    agg2_kernel<<<nbuk, B, 0, stream>>>(gbase, gcnt, binned, m2q, dinv, b2, out, n);
}